// Round 1
// baseline (1856.921 us; speedup 1.0000x reference)
//
#include <hip/hip_runtime.h>
#include <stdint.h>

// ---------------------------------------------------------------------------
// TopologicalContrastiveLoss: H0 persistence (MST edge weights) of 3 point
// clouds -> 1-Wasserstein between sorted death vectors -> hinge loss.
//
// Strategy: Boruvka MST on the dense d2 matrix (equivalent to reference's
// Prim: MST unique under the total order (d2_bits, canonical_pair_index)).
// Clouds processed sequentially reusing ONE 64MB d2 buffer in d_ws.
// ---------------------------------------------------------------------------

#define NPTS 4096
#define DIMF 1024
static const unsigned long long KEY_MAX_ULL = ~0ull;

// ------------------------------ init ---------------------------------------
__global__ void k_init_global(float* __restrict__ deaths, int* __restrict__ cnt) {
  int i = blockIdx.x * blockDim.x + threadIdx.x;
  if (i < 3 * NPTS) deaths[i] = __int_as_float(0x7f800000);  // +inf pad
  if (i < 4) cnt[i] = 0;  // cnt[0..2]=death counters, cnt[3]=done flag
}

__global__ void k_init_cloud(int* __restrict__ comp,
                             unsigned long long* __restrict__ best,
                             int* __restrict__ done) {
  int i = blockIdx.x * blockDim.x + threadIdx.x;
  if (i < NPTS) { comp[i] = i; best[i] = KEY_MAX_ULL; }
  if (i == 0) *done = 0;
}

// ------------------------------ row norms ----------------------------------
__global__ __launch_bounds__(256)
void k_norms(const float* __restrict__ x, float* __restrict__ sq) {
  const int row = blockIdx.x;
  const int t = threadIdx.x;  // 256 threads, 4 floats each = 1024
  const float4 v = ((const float4*)(x + (size_t)row * DIMF))[t];
  float s = v.x * v.x + v.y * v.y + v.z * v.z + v.w * v.w;
  for (int off = 32; off > 0; off >>= 1) s += __shfl_xor(s, off, 64);
  __shared__ float ws[4];
  if ((t & 63) == 0) ws[t >> 6] = s;
  __syncthreads();
  if (t == 0) sq[row] = ws[0] + ws[1] + ws[2] + ws[3];
}

// ------------------------------ d2 = sq_i + sq_j - 2*X@X^T ------------------
#define BM 128
#define BN 128
#define BK 16

__global__ __launch_bounds__(256)
void k_gemm_d2(const float* __restrict__ X, const float* __restrict__ sq,
               float* __restrict__ d2) {
  __shared__ float As[BK][BM];
  __shared__ float Bs[BK][BN];
  const int tid = threadIdx.x;
  const int tx = tid & 15, ty = tid >> 4;
  const int i0 = blockIdx.y * BM, j0 = blockIdx.x * BN;
  float acc[8][8] = {};
  for (int k0 = 0; k0 < DIMF; k0 += BK) {
#pragma unroll
    for (int id = tid; id < 512; id += 256) {
      const int row = id >> 2;          // 0..127
      const int kk = (id & 3) << 2;     // 0,4,8,12
      const float4 a = *(const float4*)(X + (size_t)(i0 + row) * DIMF + k0 + kk);
      const float4 b = *(const float4*)(X + (size_t)(j0 + row) * DIMF + k0 + kk);
      As[kk + 0][row] = a.x; As[kk + 1][row] = a.y;
      As[kk + 2][row] = a.z; As[kk + 3][row] = a.w;
      Bs[kk + 0][row] = b.x; Bs[kk + 1][row] = b.y;
      Bs[kk + 2][row] = b.z; Bs[kk + 3][row] = b.w;
    }
    __syncthreads();
#pragma unroll
    for (int kk = 0; kk < BK; ++kk) {
      float a[8], b[8];
#pragma unroll
      for (int m = 0; m < 8; ++m) a[m] = As[kk][ty * 8 + m];
#pragma unroll
      for (int n = 0; n < 8; ++n) b[n] = Bs[kk][tx * 8 + n];
#pragma unroll
      for (int m = 0; m < 8; ++m)
#pragma unroll
        for (int n = 0; n < 8; ++n)
          acc[m][n] = fmaf(a[m], b[n], acc[m][n]);
    }
    __syncthreads();
  }
#pragma unroll
  for (int m = 0; m < 8; ++m) {
    const int i = i0 + ty * 8 + m;
    const float si = sq[i];
    const int j = j0 + tx * 8;
    float4 o0, o1;
    o0.x = fmaxf(si + sq[j + 0] - 2.f * acc[m][0], 0.f);
    o0.y = fmaxf(si + sq[j + 1] - 2.f * acc[m][1], 0.f);
    o0.z = fmaxf(si + sq[j + 2] - 2.f * acc[m][2], 0.f);
    o0.w = fmaxf(si + sq[j + 3] - 2.f * acc[m][3], 0.f);
    o1.x = fmaxf(si + sq[j + 4] - 2.f * acc[m][4], 0.f);
    o1.y = fmaxf(si + sq[j + 5] - 2.f * acc[m][5], 0.f);
    o1.z = fmaxf(si + sq[j + 6] - 2.f * acc[m][6], 0.f);
    o1.w = fmaxf(si + sq[j + 7] - 2.f * acc[m][7], 0.f);
    *(float4*)(d2 + (size_t)i * NPTS + j) = o0;
    *(float4*)(d2 + (size_t)i * NPTS + j + 4) = o1;
  }
}

// ------------------------------ Boruvka scan --------------------------------
// One block per vertex i: min over j (comp[j]!=comp[i]) of key =
// (d2_bits << 24) | canonical_pair24.  atomicMin into best[comp[i]].
__global__ __launch_bounds__(256)
void k_scan(const float* __restrict__ d2, const int* __restrict__ comp,
            unsigned long long* __restrict__ best, const int* __restrict__ done) {
  if (*done) return;
  __shared__ int cl[NPTS];  // 16KB
  __shared__ unsigned long long red[4];
  const int i = blockIdx.x;
  const int t = threadIdx.x;
#pragma unroll
  for (int q = 0; q < 4; ++q)
    ((int4*)cl)[t + q * 256] = ((const int4*)comp)[t + q * 256];
  __syncthreads();
  const int ci = cl[i];
  const float* row = d2 + (size_t)i * NPTS;
  unsigned long long kmin = KEY_MAX_ULL;
#pragma unroll
  for (int q = 0; q < 4; ++q) {
    const int jb = t * 16 + q * 4;
    const float4 v = ((const float4*)row)[t * 4 + q];
    const float vv[4] = {v.x, v.y, v.z, v.w};
#pragma unroll
    for (int u = 0; u < 4; ++u) {
      const int j = jb + u;
      if (cl[j] != ci) {
        const unsigned long long pair =
            (i < j) ? (((unsigned long long)i << 12) | (unsigned)j)
                    : (((unsigned long long)j << 12) | (unsigned)i);
        const unsigned long long key =
            ((unsigned long long)__float_as_uint(vv[u]) << 24) | pair;
        kmin = (key < kmin) ? key : kmin;
      }
    }
  }
  for (int off = 32; off > 0; off >>= 1) {
    const unsigned long long o = __shfl_xor(kmin, off, 64);
    kmin = (o < kmin) ? o : kmin;
  }
  if ((t & 63) == 0) red[t >> 6] = kmin;
  __syncthreads();
  if (t == 0) {
    unsigned long long k2 = red[0];
    k2 = (red[1] < k2) ? red[1] : k2;
    k2 = (red[2] < k2) ? red[2] : k2;
    k2 = (red[3] < k2) ? red[3] : k2;
    if (k2 != KEY_MAX_ULL) atomicMin(best + ci, k2);
  }
}

// ------------------------------ Boruvka merge -------------------------------
// Single workgroup: hook components along selected edges (2-cycle resolution
// by min root), record death weights (dedupe mutual pairs), pointer-jump to
// new roots, write comp back, reset best, set done flag when 1 component.
__global__ __launch_bounds__(1024)
void k_merge(unsigned long long* __restrict__ best, int* __restrict__ comp,
             float* __restrict__ deaths, int* __restrict__ cnt,
             int* __restrict__ done) {
  if (*done) return;
  __shared__ int par[NPTS];  // old comp (16KB)
  __shared__ int hk[NPTS];   // hook targets (16KB)
  __shared__ int redc[16];
  const int t = threadIdx.x;
#pragma unroll
  for (int s = 0; s < 4; ++s) {
    const int v = t + s * 1024;
    par[v] = comp[v];
  }
  __syncthreads();
#pragma unroll
  for (int s = 0; s < 4; ++s) {
    const int v = t + s * 1024;
    const unsigned long long b = best[v];
    int h;
    if (b == KEY_MAX_ULL) {
      h = par[v];  // non-root (or lone root): point at old root / self
    } else {
      const int pair = (int)(b & 0xFFFFFF);
      const int a = pair >> 12, c = pair & 4095;
      const int ra = par[a], rb = par[c];
      const int so = (ra == v) ? rb : ra;  // other component's root
      const unsigned long long bs = best[so];
      const bool mutual = (bs != KEY_MAX_ULL) && ((int)(bs & 0xFFFFFF) == pair);
      bool record;
      if (mutual) {
        const int winner = (v < so) ? v : so;
        h = winner;
        record = (v == winner);  // mutual edge counted once
      } else {
        h = so;
        record = true;
      }
      if (record) {
        const float dd = __uint_as_float((unsigned)(b >> 24));
        const int slot = atomicAdd(cnt, 1);
        deaths[slot] = sqrtf(fmaxf(dd, 1e-12f));
      }
    }
    hk[v] = h;
  }
  __syncthreads();
  // pointer jumping (12 doublings cover chains up to 4096)
  for (int it = 0; it < 12; ++it) {
    int w[4];
#pragma unroll
    for (int s = 0; s < 4; ++s) {
      const int v = t + s * 1024;
      w[s] = hk[hk[v]];
    }
    __syncthreads();
#pragma unroll
    for (int s = 0; s < 4; ++s) hk[t + s * 1024] = w[s];
    __syncthreads();
  }
  int nroot = 0;
#pragma unroll
  for (int s = 0; s < 4; ++s) {
    const int v = t + s * 1024;
    comp[v] = hk[v];
    best[v] = KEY_MAX_ULL;  // reset for next round
    nroot += (hk[v] == v);
  }
  for (int off = 32; off > 0; off >>= 1) nroot += __shfl_xor(nroot, off, 64);
  if ((t & 63) == 0) redc[t >> 6] = nroot;
  __syncthreads();
  if (t == 0) {
    int tot = 0;
    for (int q = 0; q < 16; ++q) tot += redc[q];
    if (tot == 1) *done = 1;
  }
}

// ------------------------------ sort (bitonic, 4096 in LDS) -----------------
__global__ __launch_bounds__(1024)
void k_sort(float* __restrict__ deaths) {
  __shared__ float s[NPTS];
  float* g = deaths + (size_t)blockIdx.x * NPTS;
  const int t = threadIdx.x;
#pragma unroll
  for (int q = 0; q < 4; ++q) s[t + q * 1024] = g[t + q * 1024];
  for (int k = 2; k <= NPTS; k <<= 1) {
    for (int j = k >> 1; j > 0; j >>= 1) {
      __syncthreads();
#pragma unroll
      for (int q = 0; q < 4; ++q) {
        const int i = t + q * 1024;
        const int ixj = i ^ j;
        if (ixj > i) {
          const float a = s[i], b = s[ixj];
          const bool up = ((i & k) == 0);
          if ((a > b) == up) { s[i] = b; s[ixj] = a; }
        }
      }
    }
  }
  __syncthreads();
#pragma unroll
  for (int q = 0; q < 4; ++q) g[t + q * 1024] = s[t + q * 1024];
}

// ------------------------------ final loss ----------------------------------
__global__ __launch_bounds__(1024)
void k_final(const float* __restrict__ deaths, float* __restrict__ out) {
  const float* a = deaths;
  const float* p = deaths + NPTS;
  const float* n = deaths + 2 * NPTS;
  const int t = threadIdx.x;
  float s1 = 0.f, s2 = 0.f;
  for (int i = t; i < NPTS - 1; i += 1024) {  // 4095 real deaths; slot 4095=+inf
    s1 += fabsf(a[i] - p[i]);
    s2 += fabsf(a[i] - n[i]);
  }
  for (int off = 32; off > 0; off >>= 1) {
    s1 += __shfl_xor(s1, off, 64);
    s2 += __shfl_xor(s2, off, 64);
  }
  __shared__ float r1[16], r2[16];
  if ((t & 63) == 0) { r1[t >> 6] = s1; r2[t >> 6] = s2; }
  __syncthreads();
  if (t == 0) {
    float t1 = 0.f, t2 = 0.f;
    for (int q = 0; q < 16; ++q) { t1 += r1[q]; t2 += r2[q]; }
    out[0] = fmaxf(t1 - t2 + 1.0f, 0.0f);
  }
}

__global__ void k_fail(float* out) { if (threadIdx.x == 0) out[0] = 0.f; }

// ------------------------------ launch --------------------------------------
extern "C" void kernel_launch(void* const* d_in, const int* in_sizes, int n_in,
                              void* d_out, int out_size, void* d_ws, size_t ws_size,
                              hipStream_t stream) {
  const float* xs[3] = {(const float*)d_in[0], (const float*)d_in[1],
                        (const float*)d_in[2]};
  char* ws = (char*)d_ws;
  const size_t d2_bytes = (size_t)NPTS * NPTS * 4;  // 64MB
  const size_t need = d2_bytes + NPTS * 4 /*sq*/ + NPTS * 4 /*comp*/ +
                      NPTS * 8 /*best*/ + 3 * NPTS * 4 /*deaths*/ + 64;
  if (ws_size < need) {  // cannot run; deterministic fallback (will fail check)
    k_fail<<<1, 64, 0, stream>>>((float*)d_out);
    return;
  }
  float* d2 = (float*)ws;
  float* sq = (float*)(ws + d2_bytes);
  int* comp = (int*)(ws + d2_bytes + NPTS * 4);
  unsigned long long* best = (unsigned long long*)(ws + d2_bytes + NPTS * 8);
  float* deaths = (float*)(ws + d2_bytes + NPTS * 16);
  int* cnt = (int*)(ws + d2_bytes + NPTS * 16 + 3 * NPTS * 4);
  int* done = cnt + 3;

  k_init_global<<<48, 256, 0, stream>>>(deaths, cnt);
  for (int c = 0; c < 3; ++c) {
    k_norms<<<NPTS, 256, 0, stream>>>(xs[c], sq);
    k_init_cloud<<<16, 256, 0, stream>>>(comp, best, done);
    k_gemm_d2<<<dim3(NPTS / BN, NPTS / BM), 256, 0, stream>>>(xs[c], sq, d2);
    for (int r = 0; r < 12; ++r) {
      k_scan<<<NPTS, 256, 0, stream>>>(d2, comp, best, done);
      k_merge<<<1, 1024, 0, stream>>>(best, comp, deaths + c * NPTS, cnt + c, done);
    }
  }
  k_sort<<<3, 1024, 0, stream>>>(deaths);
  k_final<<<1, 1024, 0, stream>>>(deaths, (float*)d_out);
}

// Round 2
// 1066.483 us; speedup vs baseline: 1.7412x; 1.7412x over previous
//
#include <hip/hip_runtime.h>
#include <stdint.h>

// ---------------------------------------------------------------------------
// TopologicalContrastiveLoss: H0 persistence (MST edge weights) of 3 point
// clouds -> 1-Wasserstein between sorted death vectors -> hinge loss.
//
// R2: replace fp32 vector GEMM with split-bf16 MFMA GEMM (x = hi + lo):
//   X@X^T ~= Hi@Hi^T + Lo@Hi^T + Hi@Lo^T   (lo*lo term negligible)
// realized as one virtual-K=3072 bf16 GEMM, A k-blocks [hi,lo,hi],
// B k-blocks [hi,hi,lo]. m97-style structure: 128x128 tile, BK=32,
// global_load_lds width=16, 16x16x32 bf16 MFMA, 4 waves / 2x2 wave grid.
// ---------------------------------------------------------------------------

#define NPTS 4096
#define DIMF 1024
typedef unsigned short u16;
static const unsigned long long KEY_MAX_ULL = ~0ull;

typedef __bf16 bf16x8 __attribute__((ext_vector_type(8)));
typedef float f32x4 __attribute__((ext_vector_type(4)));

#define GLOAD_LDS16(g, l)                                                      \
  __builtin_amdgcn_global_load_lds(                                            \
      (const __attribute__((address_space(1))) void*)(g),                      \
      (__attribute__((address_space(3))) void*)(l), 16, 0, 0)

__device__ __forceinline__ u16 f2bf(float f) {
  unsigned u = __float_as_uint(f);
  u = u + 0x7fffu + ((u >> 16) & 1u);  // RNE
  return (u16)(u >> 16);
}
__device__ __forceinline__ float bf2f(u16 h) {
  return __uint_as_float(((unsigned)h) << 16);
}

// ------------------------------ init ---------------------------------------
__global__ void k_init_global(float* __restrict__ deaths, int* __restrict__ cnt) {
  int i = blockIdx.x * blockDim.x + threadIdx.x;
  if (i < 3 * NPTS) deaths[i] = __int_as_float(0x7f800000);  // +inf pad
  if (i < 4) cnt[i] = 0;  // cnt[0..2]=death counters, cnt[3]=done flag
}

__global__ void k_init_cloud(int* __restrict__ comp,
                             unsigned long long* __restrict__ best,
                             int* __restrict__ done) {
  int i = blockIdx.x * blockDim.x + threadIdx.x;
  if (i < NPTS) { comp[i] = i; best[i] = KEY_MAX_ULL; }
  if (i == 0) *done = 0;
}

// ------------------------------ split x -> hi/lo bf16 -----------------------
__global__ __launch_bounds__(256)
void k_split(const float* __restrict__ x, u16* __restrict__ hi,
             u16* __restrict__ lo) {
  const int i = blockIdx.x * 256 + threadIdx.x;  // one float4 per thread
  const float4 v = ((const float4*)x)[i];
  ushort4 h, l;
  h.x = f2bf(v.x); l.x = f2bf(v.x - bf2f(h.x));
  h.y = f2bf(v.y); l.y = f2bf(v.y - bf2f(h.y));
  h.z = f2bf(v.z); l.z = f2bf(v.z - bf2f(h.z));
  h.w = f2bf(v.w); l.w = f2bf(v.w - bf2f(h.w));
  ((ushort4*)hi)[i] = h;
  ((ushort4*)lo)[i] = l;
}

// ------------------------------ row norms ----------------------------------
__global__ __launch_bounds__(256)
void k_norms(const float* __restrict__ x, float* __restrict__ sq) {
  const int row = blockIdx.x;
  const int t = threadIdx.x;  // 256 threads, 4 floats each = 1024
  const float4 v = ((const float4*)(x + (size_t)row * DIMF))[t];
  float s = v.x * v.x + v.y * v.y + v.z * v.z + v.w * v.w;
  for (int off = 32; off > 0; off >>= 1) s += __shfl_xor(s, off, 64);
  __shared__ float ws[4];
  if ((t & 63) == 0) ws[t >> 6] = s;
  __syncthreads();
  if (t == 0) sq[row] = ws[0] + ws[1] + ws[2] + ws[3];
}

// ------------------------------ MFMA GEMM: d2 -------------------------------
// d2[i][j] = max(sq[i]+sq[j]-2*(HiHi+LoHi+HiLo), 0). Virtual K = 3072.
__global__ __launch_bounds__(256)
void k_gemm_mfma(const u16* __restrict__ hi, const u16* __restrict__ lo,
                 const float* __restrict__ sq, float* __restrict__ d2) {
  __shared__ u16 smem[8192];  // As 128x32 (8KB) + Bs 128x32 (8KB)
  u16* As = smem;
  u16* Bs = smem + 4096;
  const int t = threadIdx.x;
  const int w = t >> 6, l = t & 63;
  const int wm = w >> 1, wn = w & 1;           // 2x2 wave grid, 64x64 each
  const int ml = l & 15, kq = l >> 4;          // fragment row / k-quad
  const int i0 = blockIdx.y * 128, j0 = blockIdx.x * 128;

  // staging addresses: thread t covers row t>>2 (+64 for q=1), 16B chunk t&3
  const int srow = t >> 2, schk = t & 3;
  // LDS byte offsets: t*16 (+4096 bytes for q=1) -- matches wave-uniform base
  char* ldsA0 = (char*)As + t * 16;
  char* ldsB0 = (char*)Bs + t * 16;

  f32x4 acc[4][4];
#pragma unroll
  for (int a = 0; a < 4; ++a)
#pragma unroll
    for (int b = 0; b < 4; ++b) acc[a][b] = (f32x4)0.f;

  for (int k0 = 0; k0 < 3072; k0 += 32) {
    const u16* SA = ((k0 >> 10) == 1) ? lo : hi;
    const u16* SB = ((k0 >> 10) == 2) ? lo : hi;
    const int kc = k0 & 1023;
    __syncthreads();  // previous iter's compute done before overwrite
    {
      const u16* ga0 = SA + (size_t)(i0 + srow) * DIMF + kc + schk * 8;
      const u16* ga1 = SA + (size_t)(i0 + srow + 64) * DIMF + kc + schk * 8;
      const u16* gb0 = SB + (size_t)(j0 + srow) * DIMF + kc + schk * 8;
      const u16* gb1 = SB + (size_t)(j0 + srow + 64) * DIMF + kc + schk * 8;
      GLOAD_LDS16(ga0, ldsA0);
      GLOAD_LDS16(ga1, ldsA0 + 4096);
      GLOAD_LDS16(gb0, ldsB0);
      GLOAD_LDS16(gb1, ldsB0 + 4096);
    }
    asm volatile("s_waitcnt vmcnt(0)" ::: "memory");
    __syncthreads();

    const char* Ab = (const char*)As + (wm * 64 + ml) * 64 + kq * 16;
    const char* Bb = (const char*)Bs + (wn * 64 + ml) * 64 + kq * 16;
    bf16x8 af[4], bf[4];
#pragma unroll
    for (int mt = 0; mt < 4; ++mt) af[mt] = *(const bf16x8*)(Ab + mt * 1024);
#pragma unroll
    for (int nt = 0; nt < 4; ++nt) bf[nt] = *(const bf16x8*)(Bb + nt * 1024);
#pragma unroll
    for (int mt = 0; mt < 4; ++mt)
#pragma unroll
      for (int nt = 0; nt < 4; ++nt)
        acc[mt][nt] = __builtin_amdgcn_mfma_f32_16x16x32_bf16(
            af[mt], bf[nt], acc[mt][nt], 0, 0, 0);
  }

  // epilogue: C/D layout col=lane&15, row=(lane>>4)*4+reg
  float sr[4][4], sc[4];
#pragma unroll
  for (int mt = 0; mt < 4; ++mt)
#pragma unroll
    for (int r = 0; r < 4; ++r)
      sr[mt][r] = sq[i0 + wm * 64 + mt * 16 + kq * 4 + r];
#pragma unroll
  for (int nt = 0; nt < 4; ++nt) sc[nt] = sq[j0 + wn * 64 + nt * 16 + ml];
#pragma unroll
  for (int mt = 0; mt < 4; ++mt) {
#pragma unroll
    for (int nt = 0; nt < 4; ++nt) {
      const int col = j0 + wn * 64 + nt * 16 + ml;
#pragma unroll
      for (int r = 0; r < 4; ++r) {
        const int row = i0 + wm * 64 + mt * 16 + kq * 4 + r;
        const float v = fmaxf(sr[mt][r] + sc[nt] - 2.f * acc[mt][nt][r], 0.f);
        d2[(size_t)row * NPTS + col] = v;
      }
    }
  }
}

// ------------------------------ fp32 GEMM fallback --------------------------
#define BM 128
#define BN 128
#define BK 16
__global__ __launch_bounds__(256)
void k_gemm_d2(const float* __restrict__ X, const float* __restrict__ sq,
               float* __restrict__ d2) {
  __shared__ float As[BK][BM];
  __shared__ float Bs[BK][BN];
  const int tid = threadIdx.x;
  const int tx = tid & 15, ty = tid >> 4;
  const int i0 = blockIdx.y * BM, j0 = blockIdx.x * BN;
  float acc[8][8] = {};
  for (int k0 = 0; k0 < DIMF; k0 += BK) {
#pragma unroll
    for (int id = tid; id < 512; id += 256) {
      const int row = id >> 2;
      const int kk = (id & 3) << 2;
      const float4 a = *(const float4*)(X + (size_t)(i0 + row) * DIMF + k0 + kk);
      const float4 b = *(const float4*)(X + (size_t)(j0 + row) * DIMF + k0 + kk);
      As[kk + 0][row] = a.x; As[kk + 1][row] = a.y;
      As[kk + 2][row] = a.z; As[kk + 3][row] = a.w;
      Bs[kk + 0][row] = b.x; Bs[kk + 1][row] = b.y;
      Bs[kk + 2][row] = b.z; Bs[kk + 3][row] = b.w;
    }
    __syncthreads();
#pragma unroll
    for (int kk = 0; kk < BK; ++kk) {
      float a[8], b[8];
#pragma unroll
      for (int m = 0; m < 8; ++m) a[m] = As[kk][ty * 8 + m];
#pragma unroll
      for (int n = 0; n < 8; ++n) b[n] = Bs[kk][tx * 8 + n];
#pragma unroll
      for (int m = 0; m < 8; ++m)
#pragma unroll
        for (int n = 0; n < 8; ++n)
          acc[m][n] = fmaf(a[m], b[n], acc[m][n]);
    }
    __syncthreads();
  }
#pragma unroll
  for (int m = 0; m < 8; ++m) {
    const int i = i0 + ty * 8 + m;
    const float si = sq[i];
    const int j = j0 + tx * 8;
    float4 o0, o1;
    o0.x = fmaxf(si + sq[j + 0] - 2.f * acc[m][0], 0.f);
    o0.y = fmaxf(si + sq[j + 1] - 2.f * acc[m][1], 0.f);
    o0.z = fmaxf(si + sq[j + 2] - 2.f * acc[m][2], 0.f);
    o0.w = fmaxf(si + sq[j + 3] - 2.f * acc[m][3], 0.f);
    o1.x = fmaxf(si + sq[j + 4] - 2.f * acc[m][4], 0.f);
    o1.y = fmaxf(si + sq[j + 5] - 2.f * acc[m][5], 0.f);
    o1.z = fmaxf(si + sq[j + 6] - 2.f * acc[m][6], 0.f);
    o1.w = fmaxf(si + sq[j + 7] - 2.f * acc[m][7], 0.f);
    *(float4*)(d2 + (size_t)i * NPTS + j) = o0;
    *(float4*)(d2 + (size_t)i * NPTS + j + 4) = o1;
  }
}

// ------------------------------ Boruvka scan --------------------------------
__global__ __launch_bounds__(256)
void k_scan(const float* __restrict__ d2, const int* __restrict__ comp,
            unsigned long long* __restrict__ best, const int* __restrict__ done) {
  if (*done) return;
  __shared__ int cl[NPTS];  // 16KB
  __shared__ unsigned long long red[4];
  const int i = blockIdx.x;
  const int t = threadIdx.x;
#pragma unroll
  for (int q = 0; q < 4; ++q)
    ((int4*)cl)[t + q * 256] = ((const int4*)comp)[t + q * 256];
  __syncthreads();
  const int ci = cl[i];
  const float* row = d2 + (size_t)i * NPTS;
  unsigned long long kmin = KEY_MAX_ULL;
#pragma unroll
  for (int q = 0; q < 4; ++q) {
    const int jb = t * 16 + q * 4;
    const float4 v = ((const float4*)row)[t * 4 + q];
    const float vv[4] = {v.x, v.y, v.z, v.w};
#pragma unroll
    for (int u = 0; u < 4; ++u) {
      const int j = jb + u;
      if (cl[j] != ci) {
        const unsigned long long pair =
            (i < j) ? (((unsigned long long)i << 12) | (unsigned)j)
                    : (((unsigned long long)j << 12) | (unsigned)i);
        const unsigned long long key =
            ((unsigned long long)__float_as_uint(vv[u]) << 24) | pair;
        kmin = (key < kmin) ? key : kmin;
      }
    }
  }
  for (int off = 32; off > 0; off >>= 1) {
    const unsigned long long o = __shfl_xor(kmin, off, 64);
    kmin = (o < kmin) ? o : kmin;
  }
  if ((t & 63) == 0) red[t >> 6] = kmin;
  __syncthreads();
  if (t == 0) {
    unsigned long long k2 = red[0];
    k2 = (red[1] < k2) ? red[1] : k2;
    k2 = (red[2] < k2) ? red[2] : k2;
    k2 = (red[3] < k2) ? red[3] : k2;
    if (k2 != KEY_MAX_ULL) atomicMin(best + ci, k2);
  }
}

// ------------------------------ Boruvka merge -------------------------------
__global__ __launch_bounds__(1024)
void k_merge(unsigned long long* __restrict__ best, int* __restrict__ comp,
             float* __restrict__ deaths, int* __restrict__ cnt,
             int* __restrict__ done) {
  if (*done) return;
  __shared__ int par[NPTS];
  __shared__ int hk[NPTS];
  __shared__ int redc[16];
  const int t = threadIdx.x;
#pragma unroll
  for (int s = 0; s < 4; ++s) {
    const int v = t + s * 1024;
    par[v] = comp[v];
  }
  __syncthreads();
#pragma unroll
  for (int s = 0; s < 4; ++s) {
    const int v = t + s * 1024;
    const unsigned long long b = best[v];
    int h;
    if (b == KEY_MAX_ULL) {
      h = par[v];
    } else {
      const int pair = (int)(b & 0xFFFFFF);
      const int a = pair >> 12, c = pair & 4095;
      const int ra = par[a], rb = par[c];
      const int so = (ra == v) ? rb : ra;
      const unsigned long long bs = best[so];
      const bool mutual = (bs != KEY_MAX_ULL) && ((int)(bs & 0xFFFFFF) == pair);
      bool record;
      if (mutual) {
        const int winner = (v < so) ? v : so;
        h = winner;
        record = (v == winner);
      } else {
        h = so;
        record = true;
      }
      if (record) {
        const float dd = __uint_as_float((unsigned)(b >> 24));
        const int slot = atomicAdd(cnt, 1);
        deaths[slot] = sqrtf(fmaxf(dd, 1e-12f));
      }
    }
    hk[v] = h;
  }
  __syncthreads();
  for (int it = 0; it < 12; ++it) {
    int w[4];
#pragma unroll
    for (int s = 0; s < 4; ++s) {
      const int v = t + s * 1024;
      w[s] = hk[hk[v]];
    }
    __syncthreads();
#pragma unroll
    for (int s = 0; s < 4; ++s) hk[t + s * 1024] = w[s];
    __syncthreads();
  }
  int nroot = 0;
#pragma unroll
  for (int s = 0; s < 4; ++s) {
    const int v = t + s * 1024;
    comp[v] = hk[v];
    best[v] = KEY_MAX_ULL;
    nroot += (hk[v] == v);
  }
  for (int off = 32; off > 0; off >>= 1) nroot += __shfl_xor(nroot, off, 64);
  if ((t & 63) == 0) redc[t >> 6] = nroot;
  __syncthreads();
  if (t == 0) {
    int tot = 0;
    for (int q = 0; q < 16; ++q) tot += redc[q];
    if (tot == 1) *done = 1;
  }
}

// ------------------------------ sort (bitonic, 4096 in LDS) -----------------
__global__ __launch_bounds__(1024)
void k_sort(float* __restrict__ deaths) {
  __shared__ float s[NPTS];
  float* g = deaths + (size_t)blockIdx.x * NPTS;
  const int t = threadIdx.x;
#pragma unroll
  for (int q = 0; q < 4; ++q) s[t + q * 1024] = g[t + q * 1024];
  for (int k = 2; k <= NPTS; k <<= 1) {
    for (int j = k >> 1; j > 0; j >>= 1) {
      __syncthreads();
#pragma unroll
      for (int q = 0; q < 4; ++q) {
        const int i = t + q * 1024;
        const int ixj = i ^ j;
        if (ixj > i) {
          const float a = s[i], b = s[ixj];
          const bool up = ((i & k) == 0);
          if ((a > b) == up) { s[i] = b; s[ixj] = a; }
        }
      }
    }
  }
  __syncthreads();
#pragma unroll
  for (int q = 0; q < 4; ++q) g[t + q * 1024] = s[t + q * 1024];
}

// ------------------------------ final loss ----------------------------------
__global__ __launch_bounds__(1024)
void k_final(const float* __restrict__ deaths, float* __restrict__ out) {
  const float* a = deaths;
  const float* p = deaths + NPTS;
  const float* n = deaths + 2 * NPTS;
  const int t = threadIdx.x;
  float s1 = 0.f, s2 = 0.f;
  for (int i = t; i < NPTS - 1; i += 1024) {
    s1 += fabsf(a[i] - p[i]);
    s2 += fabsf(a[i] - n[i]);
  }
  for (int off = 32; off > 0; off >>= 1) {
    s1 += __shfl_xor(s1, off, 64);
    s2 += __shfl_xor(s2, off, 64);
  }
  __shared__ float r1[16], r2[16];
  if ((t & 63) == 0) { r1[t >> 6] = s1; r2[t >> 6] = s2; }
  __syncthreads();
  if (t == 0) {
    float t1 = 0.f, t2 = 0.f;
    for (int q = 0; q < 16; ++q) { t1 += r1[q]; t2 += r2[q]; }
    out[0] = fmaxf(t1 - t2 + 1.0f, 0.0f);
  }
}

__global__ void k_fail(float* out) { if (threadIdx.x == 0) out[0] = 0.f; }

// ------------------------------ launch --------------------------------------
extern "C" void kernel_launch(void* const* d_in, const int* in_sizes, int n_in,
                              void* d_out, int out_size, void* d_ws, size_t ws_size,
                              hipStream_t stream) {
  const float* xs[3] = {(const float*)d_in[0], (const float*)d_in[1],
                        (const float*)d_in[2]};
  char* ws = (char*)d_ws;
  const size_t d2_bytes = (size_t)NPTS * NPTS * 4;             // 64MB
  const size_t hilo_bytes = (size_t)NPTS * DIMF * 2;           // 8MB each
  const size_t small = NPTS * 4 /*sq*/ + NPTS * 4 /*comp*/ + NPTS * 8 /*best*/ +
                       3 * NPTS * 4 /*deaths*/ + 64;
  const size_t need_fp32 = d2_bytes + small;
  const size_t need_mfma = d2_bytes + 2 * hilo_bytes + small;
  if (ws_size < need_fp32) {
    k_fail<<<1, 64, 0, stream>>>((float*)d_out);
    return;
  }
  const bool use_mfma = (ws_size >= need_mfma);
  const size_t tail0 = use_mfma ? (d2_bytes + 2 * hilo_bytes) : d2_bytes;

  float* d2 = (float*)ws;
  u16* hi = (u16*)(ws + d2_bytes);
  u16* lo = (u16*)(ws + d2_bytes + hilo_bytes);
  float* sq = (float*)(ws + tail0);
  int* comp = (int*)(ws + tail0 + NPTS * 4);
  unsigned long long* best = (unsigned long long*)(ws + tail0 + NPTS * 8);
  float* deaths = (float*)(ws + tail0 + NPTS * 16);
  int* cnt = (int*)(ws + tail0 + NPTS * 16 + 3 * NPTS * 4);
  int* done = cnt + 3;

  k_init_global<<<48, 256, 0, stream>>>(deaths, cnt);
  for (int c = 0; c < 3; ++c) {
    k_norms<<<NPTS, 256, 0, stream>>>(xs[c], sq);
    k_init_cloud<<<16, 256, 0, stream>>>(comp, best, done);
    if (use_mfma) {
      k_split<<<4096, 256, 0, stream>>>(xs[c], hi, lo);
      k_gemm_mfma<<<dim3(NPTS / 128, NPTS / 128), 256, 0, stream>>>(hi, lo, sq, d2);
    } else {
      k_gemm_d2<<<dim3(NPTS / BN, NPTS / BM), 256, 0, stream>>>(xs[c], sq, d2);
    }
    for (int r = 0; r < 12; ++r) {
      k_scan<<<NPTS, 256, 0, stream>>>(d2, comp, best, done);
      k_merge<<<1, 1024, 0, stream>>>(best, comp, deaths + c * NPTS, cnt + c, done);
    }
  }
  k_sort<<<3, 1024, 0, stream>>>(deaths);
  k_final<<<1, 1024, 0, stream>>>(deaths, (float*)d_out);
}